// Round 2
// baseline (12653.761 us; speedup 1.0000x reference)
//
#include <hip/hip_runtime.h>

typedef unsigned short u16;
typedef unsigned int u32;
typedef __attribute__((ext_vector_type(8))) short bf16x8;   // 8 bf16 = 4 VGPRs (guide §3)
typedef __attribute__((ext_vector_type(4))) float f32x4;

namespace {
constexpr int kB = 64, kT = 1024, kI = 64, kH = 512, kO = 24;
constexpr int kBH = kB * kH;                 // 32768 elements per h buffer (bf16)
constexpr int kNWG = 132;                    // 64 L1 + 64 L2 + 4 OUT
constexpr int kTicks = kT + 2;               // 1026 (skewed pipeline)
constexpr unsigned kBarOff = 5u * (unsigned)kBH * 2u;  // bytes: 3 h1 bufs + 2 h2 bufs = 327680
}

__device__ __forceinline__ u16 f2bf(float f) {   // round-to-nearest-even
  union { float f; u32 u; } c; c.f = f;
  u32 u = c.u + 0x7FFFu + ((c.u >> 16) & 1u);
  return (u16)(u >> 16);
}
__device__ __forceinline__ float sigf(float x) { return 1.0f / (1.0f + __expf(-x)); }
__device__ __forceinline__ float tanhf_(float x) {
  float e = __expf(2.0f * x); return 1.0f - 2.0f / (e + 1.0f);  // safe at +-inf
}
// load 8 consecutive fp32, convert to a bf16x8 MFMA fragment (RNE)
__device__ __forceinline__ bf16x8 cvt8(const float* p) {
  const float4 f0 = *reinterpret_cast<const float4*>(p);
  const float4 f1 = *reinterpret_cast<const float4*>(p + 4);
  bf16x8 r;
  r[0] = (short)f2bf(f0.x); r[1] = (short)f2bf(f0.y);
  r[2] = (short)f2bf(f0.z); r[3] = (short)f2bf(f0.w);
  r[4] = (short)f2bf(f1.x); r[5] = (short)f2bf(f1.y);
  r[6] = (short)f2bf(f1.z); r[7] = (short)f2bf(f1.w);
  return r;
}
// load 8 consecutive bf16 (internal h format)
__device__ __forceinline__ bf16x8 ld8(const u16* p) {
  return *reinterpret_cast<const bf16x8*>(p);
}
__device__ __forceinline__ f32x4 mfma(bf16x8 a, bf16x8 b, f32x4 c) {
  return __builtin_amdgcn_mfma_f32_16x16x32_bf16(a, b, c, 0, 0, 0);
}

// Grid barrier via monotonically increasing generation counter.
// Works with a plain launch as long as all kNWG blocks are co-resident
// (132 blocks <= 256 CUs at 1 block/CU -> guaranteed placement).
__device__ __forceinline__ void gbar(u32* bar, u32* gen, u32 expected) {
  __syncthreads();   // drains vmcnt -> this block's h stores are in L2
  if (threadIdx.x == 0) {
    __builtin_amdgcn_fence(__ATOMIC_RELEASE, "agent");   // publish this XCD's writes
    u32 prev = __hip_atomic_fetch_add(bar, 1u, __ATOMIC_RELAXED, __HIP_MEMORY_SCOPE_AGENT);
    if (prev == (u32)(kNWG - 1)) {
      __hip_atomic_store(bar, 0u, __ATOMIC_RELAXED, __HIP_MEMORY_SCOPE_AGENT);
      __hip_atomic_store(gen, expected, __ATOMIC_RELEASE, __HIP_MEMORY_SCOPE_AGENT);
    } else {
      while (__hip_atomic_load(gen, __ATOMIC_RELAXED, __HIP_MEMORY_SCOPE_AGENT) < expected) {
        __builtin_amdgcn_s_sleep(2);
      }
    }
    __builtin_amdgcn_fence(__ATOMIC_ACQUIRE, "agent");   // invalidate stale L1/L2 lines
  }
  __syncthreads();
}

// Roles (grid of 132 x 256 threads):
//   wg   0..63 : layer-1 GRU, 16 hidden units x 32 batch each. tick k -> h1[k]
//   wg  64..127: layer-2 GRU, 16 units x 32 batch.             tick k -> h2[k-1]
//   wg 128..131: output head, 16 batch each.                   tick k -> out[k-2]
// h1: 3 bufs (mod-3), h2: 2 bufs (mod-2), bf16 [B][H] in d_ws, zeroed by memset.
// MFMA 16x16x32 frag conventions (guide §3, m89/m118-verified):
//   A: m=lane&15, k=quad*8+j ; B: n=lane&15, k=quad*8+j ; C/D: col(n)=lane&15, row(m)=quad*4+reg
__global__ __launch_bounds__(256, 1) void stackgru(
    const float* __restrict__ x,
    const float* __restrict__ wih1, const float* __restrict__ whh1,
    const float* __restrict__ bih1, const float* __restrict__ bhh1,
    const float* __restrict__ wih2, const float* __restrict__ whh2,
    const float* __restrict__ bih2, const float* __restrict__ bhh2,
    const float* __restrict__ wo1, const float* __restrict__ bo1,
    const float* __restrict__ wo2, const float* __restrict__ bo2,
    float* __restrict__ out, u16* __restrict__ hbuf, u32* __restrict__ bar)
{
  __shared__ float xch[2][3][64][4];   // cross-wave preact exchange
  const int wg = blockIdx.x;
  const int tid = threadIdx.x;
  const int lane = tid & 63;
  const int wid = tid >> 6;
  const int l15 = lane & 15;
  const int q = lane >> 4;
  u32* gen = bar + 16;                 // 64B away from counter

  u16* h1b = hbuf;                     // 3 * kBH
  u16* h2b = hbuf + 3 * kBH;           // 2 * kBH

  if (wg < 64) {
    // ---------------- layer 1 ----------------
    const int u0 = (wg & 31) * 16, b0 = (wg >> 5) * 32;
    const int ntl = wid & 1, kh = wid >> 1;   // kh0 waves: K 0..255 + x-GEMM + update; kh1: K 256..511
    const int bb = b0 + ntl * 16 + l15;       // batch this lane produces/consumes
    bf16x8 ahh[3][8];                          // w_hh1 A-frags, resident in VGPRs
#pragma unroll
    for (int g = 0; g < 3; ++g)
#pragma unroll
      for (int c = 0; c < 8; ++c)
        ahh[g][c] = cvt8(whh1 + (g * kH + u0 + l15) * kH + (kh * 8 + c) * 32 + q * 8);
    bf16x8 aih[3][2];
    float br[4], bz[4], bni[4], bnh[4], h1l[4];
    if (kh == 0) {
#pragma unroll
      for (int g = 0; g < 3; ++g)
#pragma unroll
        for (int c = 0; c < 2; ++c)
          aih[g][c] = cvt8(wih1 + (g * kH + u0 + l15) * kI + c * 32 + q * 8);
#pragma unroll
      for (int r = 0; r < 4; ++r) {
        int u = u0 + q * 4 + r;
        br[r]  = bih1[u]          + bhh1[u];
        bz[r]  = bih1[kH + u]     + bhh1[kH + u];
        bni[r] = bih1[2 * kH + u];
        bnh[r] = bhh1[2 * kH + u];
        h1l[r] = 0.0f;                  // fp32 master copy of h1, lives in regs forever
      }
    }
    for (int k = 0; k < kTicks; ++k) {
      if (k < kT) {
        const u16* hs = h1b + ((k + 2) % 3) * kBH + bb * kH + kh * 256;  // h1[k-1]
        f32x4 a0 = {0,0,0,0}, a1 = {0,0,0,0}, a2 = {0,0,0,0};
#pragma unroll
        for (int c = 0; c < 8; ++c) {
          bf16x8 bf = ld8(hs + c * 32 + q * 8);
          a0 = mfma(ahh[0][c], bf, a0);
          a1 = mfma(ahh[1][c], bf, a1);
          a2 = mfma(ahh[2][c], bf, a2);
        }
        f32x4 x0 = {0,0,0,0}, x1 = {0,0,0,0}, x2 = {0,0,0,0};
        if (kh == 1) {
#pragma unroll
          for (int r = 0; r < 4; ++r) {
            xch[ntl][0][lane][r] = a0[r];
            xch[ntl][1][lane][r] = a1[r];
            xch[ntl][2][lane][r] = a2[r];
          }
        } else {
          const float* xs = x + (bb * kT + k) * kI + q * 8;   // gi1 = x_t @ w_ih1^T
#pragma unroll
          for (int c = 0; c < 2; ++c) {
            bf16x8 bf = cvt8(xs + c * 32);
            x0 = mfma(aih[0][c], bf, x0);
            x1 = mfma(aih[1][c], bf, x1);
            x2 = mfma(aih[2][c], bf, x2);
          }
        }
        __syncthreads();
        if (kh == 0) {
          u16 hq[4];
#pragma unroll
          for (int r = 0; r < 4; ++r) {
            float gr = a0[r] + xch[ntl][0][lane][r];
            float gz = a1[r] + xch[ntl][1][lane][r];
            float gn = a2[r] + xch[ntl][2][lane][r];
            float rr = sigf(x0[r] + gr + br[r]);
            float zz = sigf(x1[r] + gz + bz[r]);
            float nn = tanhf_(x2[r] + bni[r] + rr * (gn + bnh[r]));
            float h  = (1.0f - zz) * nn + zz * h1l[r];
            h1l[r] = h; hq[r] = f2bf(h);
          }
          *reinterpret_cast<ushort4*>(h1b + (k % 3) * kBH + bb * kH + u0 + q * 4) =
              make_ushort4(hq[0], hq[1], hq[2], hq[3]);
        }
      }
      gbar(bar, gen, (u32)(k + 1));
    }
  } else if (wg < 128) {
    // ---------------- layer 2 ----------------
    const int g2 = wg - 64;
    const int u0 = (g2 & 31) * 16, b0 = (g2 >> 5) * 32;
    const int ntl = wid & 1, mat = wid >> 1;  // mat0: gi2 (w_ih2) + update; mat1: gh2 (w_hh2)
    const int bb = b0 + ntl * 16 + l15;
    const float* wsrc = mat ? whh2 : wih2;
    bf16x8 af[3][16];                          // 192 VGPRs of resident weights
#pragma unroll
    for (int g = 0; g < 3; ++g)
#pragma unroll
      for (int c = 0; c < 16; ++c)
        af[g][c] = cvt8(wsrc + (g * kH + u0 + l15) * kH + c * 32 + q * 8);
    float br[4], bz[4], bni[4], bnh[4], h2l[4];
    if (mat == 0) {
#pragma unroll
      for (int r = 0; r < 4; ++r) {
        int u = u0 + q * 4 + r;
        br[r]  = bih2[u]          + bhh2[u];
        bz[r]  = bih2[kH + u]     + bhh2[kH + u];
        bni[r] = bih2[2 * kH + u];
        bnh[r] = bhh2[2 * kH + u];
        h2l[r] = 0.0f;
      }
    }
    for (int k = 0; k < kTicks; ++k) {
      if (k >= 1 && k <= kT) {
        // computing h2[k-1]: gi2 from h1[k-1] (buf (k-1)%3), gh2 from h2[k-2] (buf k%2)
        const u16* hs = (mat == 0)
            ? h1b + ((k + 2) % 3) * kBH + bb * kH
            : h2b + (k % 2) * kBH + bb * kH;
        f32x4 a0 = {0,0,0,0}, a1 = {0,0,0,0}, a2 = {0,0,0,0};
#pragma unroll
        for (int c = 0; c < 16; ++c) {
          bf16x8 bf = ld8(hs + c * 32 + q * 8);
          a0 = mfma(af[0][c], bf, a0);
          a1 = mfma(af[1][c], bf, a1);
          a2 = mfma(af[2][c], bf, a2);
        }
        if (mat == 1) {
#pragma unroll
          for (int r = 0; r < 4; ++r) {
            xch[ntl][0][lane][r] = a0[r];
            xch[ntl][1][lane][r] = a1[r];
            xch[ntl][2][lane][r] = a2[r];
          }
        }
        __syncthreads();
        if (mat == 0) {
          u16 hq[4];
#pragma unroll
          for (int r = 0; r < 4; ++r) {
            float gr = xch[ntl][0][lane][r];
            float gz = xch[ntl][1][lane][r];
            float gn = xch[ntl][2][lane][r];
            float rr = sigf(a0[r] + gr + br[r]);
            float zz = sigf(a1[r] + gz + bz[r]);
            float nn = tanhf_(a2[r] + bni[r] + rr * (gn + bnh[r]));
            float h  = (1.0f - zz) * nn + zz * h2l[r];
            h2l[r] = h; hq[r] = f2bf(h);
          }
          *reinterpret_cast<ushort4*>(h2b + ((k - 1) % 2) * kBH + bb * kH + u0 + q * 4) =
              make_ushort4(hq[0], hq[1], hq[2], hq[3]);
        }
      }
      gbar(bar, gen, (u32)(k + 1));
    }
  } else {
    // ---------------- output head ----------------
    const int g3 = wg - 128;
    const int bb = g3 * 16 + l15;
    const int mat = wid & 1, rt = wid >> 1;   // mat0: w_o1 branch + store; mat1: w_o2 branch
    const float* wo = mat ? wo2 : wo1;
    const float* bo = mat ? bo2 : bo1;
    const int row = rt * 16 + l15;            // output channel (rows >= 24 padded with 0)
    bf16x8 zf = {0,0,0,0,0,0,0,0};
    bf16x8 af[16];
#pragma unroll
    for (int c = 0; c < 16; ++c)
      af[c] = (row < kO) ? cvt8(wo + row * kH + c * 32 + q * 8) : zf;
    float bv[4];
#pragma unroll
    for (int r = 0; r < 4; ++r) {
      int o = rt * 16 + q * 4 + r;
      bv[r] = (o < kO) ? bo[o] : 0.0f;
    }
    for (int k = 0; k < kTicks; ++k) {
      if (k >= 2) {
        const int t = k - 2;  // out[t] = tanh(h1[t]@wo1^T+b) + tanh(h2[t]@wo2^T+b)
        const u16* hs = (mat == 0)
            ? h1b + (t % 3) * kBH + bb * kH
            : h2b + (t % 2) * kBH + bb * kH;
        f32x4 a0 = {0,0,0,0};
#pragma unroll
        for (int c = 0; c < 16; ++c)
          a0 = mfma(af[c], ld8(hs + c * 32 + q * 8), a0);
        float v[4];
#pragma unroll
        for (int r = 0; r < 4; ++r) v[r] = tanhf_(a0[r] + bv[r]);
        if (mat == 1) {
#pragma unroll
          for (int r = 0; r < 4; ++r) xch[rt][0][lane][r] = v[r];
        }
        __syncthreads();
        if (mat == 0) {
          int o0 = rt * 16 + q * 4;
          if (o0 < kO) {
            float4 ov;
            ov.x = v[0] + xch[rt][0][lane][0];
            ov.y = v[1] + xch[rt][0][lane][1];
            ov.z = v[2] + xch[rt][0][lane][2];
            ov.w = v[3] + xch[rt][0][lane][3];
            *reinterpret_cast<float4*>(out + (bb * kT + t) * kO + o0) = ov;
          }
        }
      }
      gbar(bar, gen, (u32)(k + 1));
    }
  }
}

extern "C" void kernel_launch(void* const* d_in, const int* in_sizes, int n_in,
                              void* d_out, int out_size, void* d_ws, size_t ws_size,
                              hipStream_t stream) {
  (void)in_sizes; (void)n_in; (void)out_size; (void)ws_size; (void)kB;
  // zero h buffers + barrier state (ws is poisoned 0xAA before every launch)
  hipMemsetAsync(d_ws, 0, kBarOff + 256, stream);
  const float* x    = (const float*)d_in[0];
  const float* wih1 = (const float*)d_in[1];
  const float* whh1 = (const float*)d_in[2];
  const float* bih1 = (const float*)d_in[3];
  const float* bhh1 = (const float*)d_in[4];
  const float* wih2 = (const float*)d_in[5];
  const float* whh2 = (const float*)d_in[6];
  const float* bih2 = (const float*)d_in[7];
  const float* bhh2 = (const float*)d_in[8];
  const float* wo1  = (const float*)d_in[9];
  const float* bo1  = (const float*)d_in[10];
  const float* wo2  = (const float*)d_in[11];
  const float* bo2  = (const float*)d_in[12];
  float* out = (float*)d_out;
  u16* hbuf  = (u16*)d_ws;
  u32* bar   = (u32*)((char*)d_ws + kBarOff);
  stackgru<<<dim3(kNWG), dim3(256), 0, stream>>>(
      x, wih1, whh1, bih1, bhh1, wih2, whh2, bih2, bhh2,
      wo1, bo1, wo2, bo2, out, hbuf, bar);
}

// Round 3
// 7976.982 us; speedup vs baseline: 1.5863x; 1.5863x over previous
//
#include <hip/hip_runtime.h>

typedef unsigned short u16;
typedef unsigned int u32;
typedef unsigned long long u64;
typedef __attribute__((ext_vector_type(8))) short bf16x8;   // 8 bf16 = 4 VGPRs (guide §3)
typedef __attribute__((ext_vector_type(4))) float f32x4;

namespace {
constexpr int kB = 64, kT = 1024, kI = 64, kH = 512, kO = 24;
constexpr int kBH = kB * kH;                 // 32768 elements per h buffer (bf16)
constexpr int kNWG = 132;                    // 64 L1 + 64 L2 + 4 OUT
constexpr int kTicks = kT + 2;               // 1026 (skewed pipeline)
constexpr unsigned kBarOff = 5u * (unsigned)kBH * 2u;  // bytes: 3 h1 bufs + 2 h2 bufs = 327680
}

__device__ __forceinline__ u16 f2bf(float f) {   // round-to-nearest-even
  union { float f; u32 u; } c; c.f = f;
  u32 u = c.u + 0x7FFFu + ((c.u >> 16) & 1u);
  return (u16)(u >> 16);
}
__device__ __forceinline__ float sigf(float x) { return 1.0f / (1.0f + __expf(-x)); }
__device__ __forceinline__ float tanhf_(float x) {
  float e = __expf(2.0f * x); return 1.0f - 2.0f / (e + 1.0f);  // safe at +-inf
}
// load 8 consecutive fp32, convert to a bf16x8 MFMA fragment (RNE)
__device__ __forceinline__ bf16x8 cvt8(const float* p) {
  const float4 f0 = *reinterpret_cast<const float4*>(p);
  const float4 f1 = *reinterpret_cast<const float4*>(p + 4);
  bf16x8 r;
  r[0] = (short)f2bf(f0.x); r[1] = (short)f2bf(f0.y);
  r[2] = (short)f2bf(f0.z); r[3] = (short)f2bf(f0.w);
  r[4] = (short)f2bf(f1.x); r[5] = (short)f2bf(f1.y);
  r[6] = (short)f2bf(f1.z); r[7] = (short)f2bf(f1.w);
  return r;
}
// coherent (cross-XCD) 16B load of 8 bf16: two relaxed agent-scope atomic u64
// loads -> global_load_dwordx2 sc0 sc1, bypasses non-coherent L2, served by
// memory-side Infinity Cache. Pipelined like normal vmcnt loads.
__device__ __forceinline__ bf16x8 ld8c(const u16* p) {
  union { bf16x8 v; u64 q[2]; } r;
  r.q[0] = __hip_atomic_load((const u64*)p,     __ATOMIC_RELAXED, __HIP_MEMORY_SCOPE_AGENT);
  r.q[1] = __hip_atomic_load((const u64*)p + 1, __ATOMIC_RELAXED, __HIP_MEMORY_SCOPE_AGENT);
  return r.v;
}
// coherent 8B store of 4 bf16 (write-through past L2 to the coherent point)
__device__ __forceinline__ void st8c(u16* p, u16 a, u16 b, u16 c, u16 d) {
  u64 v = (u64)a | ((u64)b << 16) | ((u64)c << 32) | ((u64)d << 48);
  __hip_atomic_store((u64*)p, v, __ATOMIC_RELAXED, __HIP_MEMORY_SCOPE_AGENT);
}
__device__ __forceinline__ f32x4 mfma(bf16x8 a, bf16x8 b, f32x4 c) {
  return __builtin_amdgcn_mfma_f32_16x16x32_bf16(a, b, c, 0, 0, 0);
}

// Distributed grid barrier, no RMW contention, no cache-nuking fences:
//  - arrival: one sc1 store of `val` into this WG's own slot (after
//    __syncthreads drained vmcnt -> all h stores already at the coherent point)
//  - wait: wave 0 polls all 132 slots in parallel (64 lanes x 2-3 loads, L3 hit)
// Requires all kNWG blocks co-resident: 132 blocks <= 256 CUs at 1 block/CU.
__device__ __forceinline__ void gbar(u32* slots, int wg, u32 val) {
  __syncthreads();                      // drains vmcnt(0): h stores visible at L3
  if ((threadIdx.x >> 6) == 0) {        // wave 0 only
    const int lane = threadIdx.x;
    if (lane == 0)
      __hip_atomic_store(&slots[wg], val, __ATOMIC_RELAXED, __HIP_MEMORY_SCOPE_AGENT);
    u32 a, b, c;
    do {
      a = __hip_atomic_load(&slots[lane],      __ATOMIC_RELAXED, __HIP_MEMORY_SCOPE_AGENT);
      b = __hip_atomic_load(&slots[64 + lane], __ATOMIC_RELAXED, __HIP_MEMORY_SCOPE_AGENT);
      c = (lane < 4) ? __hip_atomic_load(&slots[128 + lane], __ATOMIC_RELAXED, __HIP_MEMORY_SCOPE_AGENT)
                     : val;
    } while (!__all((a >= val) & (b >= val) & (c >= val)));
  }
  __syncthreads();                      // release waves 1..3
}

// Roles (grid of 132 x 256 threads):
//   wg   0..63 : layer-1 GRU, 16 hidden units x 32 batch each. tick k -> h1[k]
//   wg  64..127: layer-2 GRU, 16 units x 32 batch.             tick k -> h2[k-1]
//   wg 128..131: output head, 16 batch each.                   tick k -> out[k-2]
// h1: 3 bufs (mod-3), h2: 2 bufs (mod-2), bf16 [B][H] in d_ws, zeroed by memset.
// MFMA 16x16x32 frag conventions (guide §3, m89/m118-verified):
//   A: m=lane&15, k=quad*8+j ; B: n=lane&15, k=quad*8+j ; C/D: col(n)=lane&15, row(m)=quad*4+reg
__global__ __launch_bounds__(256, 1) void stackgru(
    const float* __restrict__ x,
    const float* __restrict__ wih1, const float* __restrict__ whh1,
    const float* __restrict__ bih1, const float* __restrict__ bhh1,
    const float* __restrict__ wih2, const float* __restrict__ whh2,
    const float* __restrict__ bih2, const float* __restrict__ bhh2,
    const float* __restrict__ wo1, const float* __restrict__ bo1,
    const float* __restrict__ wo2, const float* __restrict__ bo2,
    float* __restrict__ out, u16* __restrict__ hbuf, u32* __restrict__ slots)
{
  __shared__ float xch[2][3][64][4];   // cross-wave preact exchange
  const int wg = blockIdx.x;
  const int tid = threadIdx.x;
  const int lane = tid & 63;
  const int wid = tid >> 6;
  const int l15 = lane & 15;
  const int q = lane >> 4;

  u16* h1b = hbuf;                     // 3 * kBH
  u16* h2b = hbuf + 3 * kBH;           // 2 * kBH

  if (wg < 64) {
    // ---------------- layer 1 ----------------
    const int u0 = (wg & 31) * 16, b0 = (wg >> 5) * 32;
    const int ntl = wid & 1, kh = wid >> 1;   // kh0 waves: K 0..255 + x-GEMM + update; kh1: K 256..511
    const int bb = b0 + ntl * 16 + l15;       // batch this lane produces/consumes
    bf16x8 ahh[3][8];                          // w_hh1 A-frags, resident in VGPRs
#pragma unroll
    for (int g = 0; g < 3; ++g)
#pragma unroll
      for (int c = 0; c < 8; ++c)
        ahh[g][c] = cvt8(whh1 + (g * kH + u0 + l15) * kH + (kh * 8 + c) * 32 + q * 8);
    bf16x8 aih[3][2];
    float br[4], bz[4], bni[4], bnh[4], h1l[4];
    if (kh == 0) {
#pragma unroll
      for (int g = 0; g < 3; ++g)
#pragma unroll
        for (int c = 0; c < 2; ++c)
          aih[g][c] = cvt8(wih1 + (g * kH + u0 + l15) * kI + c * 32 + q * 8);
#pragma unroll
      for (int r = 0; r < 4; ++r) {
        int u = u0 + q * 4 + r;
        br[r]  = bih1[u]          + bhh1[u];
        bz[r]  = bih1[kH + u]     + bhh1[kH + u];
        bni[r] = bih1[2 * kH + u];
        bnh[r] = bhh1[2 * kH + u];
        h1l[r] = 0.0f;                  // fp32 master copy of h1, lives in regs forever
      }
    }
    for (int k = 0; k < kTicks; ++k) {
      if (k < kT) {
        const u16* hs = h1b + ((k + 2) % 3) * kBH + bb * kH + kh * 256;  // h1[k-1]
        f32x4 a0 = {0,0,0,0}, a1 = {0,0,0,0}, a2 = {0,0,0,0};
#pragma unroll
        for (int c = 0; c < 8; ++c) {
          bf16x8 bf = ld8c(hs + c * 32 + q * 8);
          a0 = mfma(ahh[0][c], bf, a0);
          a1 = mfma(ahh[1][c], bf, a1);
          a2 = mfma(ahh[2][c], bf, a2);
        }
        f32x4 x0 = {0,0,0,0}, x1 = {0,0,0,0}, x2 = {0,0,0,0};
        if (kh == 1) {
#pragma unroll
          for (int r = 0; r < 4; ++r) {
            xch[ntl][0][lane][r] = a0[r];
            xch[ntl][1][lane][r] = a1[r];
            xch[ntl][2][lane][r] = a2[r];
          }
        } else {
          const float* xs = x + (bb * kT + k) * kI + q * 8;   // gi1 = x_t @ w_ih1^T
#pragma unroll
          for (int c = 0; c < 2; ++c) {
            bf16x8 bf = cvt8(xs + c * 32);
            x0 = mfma(aih[0][c], bf, x0);
            x1 = mfma(aih[1][c], bf, x1);
            x2 = mfma(aih[2][c], bf, x2);
          }
        }
        __syncthreads();
        if (kh == 0) {
          u16 hq[4];
#pragma unroll
          for (int r = 0; r < 4; ++r) {
            float gr = a0[r] + xch[ntl][0][lane][r];
            float gz = a1[r] + xch[ntl][1][lane][r];
            float gn = a2[r] + xch[ntl][2][lane][r];
            float rr = sigf(x0[r] + gr + br[r]);
            float zz = sigf(x1[r] + gz + bz[r]);
            float nn = tanhf_(x2[r] + bni[r] + rr * (gn + bnh[r]));
            float h  = (1.0f - zz) * nn + zz * h1l[r];
            h1l[r] = h; hq[r] = f2bf(h);
          }
          st8c(h1b + (k % 3) * kBH + bb * kH + u0 + q * 4, hq[0], hq[1], hq[2], hq[3]);
        }
      }
      gbar(slots, wg, (u32)(k + 1));
    }
  } else if (wg < 128) {
    // ---------------- layer 2 ----------------
    const int g2 = wg - 64;
    const int u0 = (g2 & 31) * 16, b0 = (g2 >> 5) * 32;
    const int ntl = wid & 1, mat = wid >> 1;  // mat0: gi2 (w_ih2) + update; mat1: gh2 (w_hh2)
    const int bb = b0 + ntl * 16 + l15;
    const float* wsrc = mat ? whh2 : wih2;
    bf16x8 af[3][16];                          // 192 VGPRs of resident weights
#pragma unroll
    for (int g = 0; g < 3; ++g)
#pragma unroll
      for (int c = 0; c < 16; ++c)
        af[g][c] = cvt8(wsrc + (g * kH + u0 + l15) * kH + c * 32 + q * 8);
    float br[4], bz[4], bni[4], bnh[4], h2l[4];
    if (mat == 0) {
#pragma unroll
      for (int r = 0; r < 4; ++r) {
        int u = u0 + q * 4 + r;
        br[r]  = bih2[u]          + bhh2[u];
        bz[r]  = bih2[kH + u]     + bhh2[kH + u];
        bni[r] = bih2[2 * kH + u];
        bnh[r] = bhh2[2 * kH + u];
        h2l[r] = 0.0f;
      }
    }
    for (int k = 0; k < kTicks; ++k) {
      if (k >= 1 && k <= kT) {
        // computing h2[k-1]: gi2 from h1[k-1] (buf (k-1)%3), gh2 from h2[k-2] (buf k%2)
        const u16* hs = (mat == 0)
            ? h1b + ((k + 2) % 3) * kBH + bb * kH
            : h2b + (k % 2) * kBH + bb * kH;
        f32x4 a0 = {0,0,0,0}, a1 = {0,0,0,0}, a2 = {0,0,0,0};
#pragma unroll
        for (int c = 0; c < 16; ++c) {
          bf16x8 bf = ld8c(hs + c * 32 + q * 8);
          a0 = mfma(af[0][c], bf, a0);
          a1 = mfma(af[1][c], bf, a1);
          a2 = mfma(af[2][c], bf, a2);
        }
        if (mat == 1) {
#pragma unroll
          for (int r = 0; r < 4; ++r) {
            xch[ntl][0][lane][r] = a0[r];
            xch[ntl][1][lane][r] = a1[r];
            xch[ntl][2][lane][r] = a2[r];
          }
        }
        __syncthreads();
        if (mat == 0) {
          u16 hq[4];
#pragma unroll
          for (int r = 0; r < 4; ++r) {
            float gr = xch[ntl][0][lane][r];
            float gz = xch[ntl][1][lane][r];
            float gn = xch[ntl][2][lane][r];
            float rr = sigf(a0[r] + gr + br[r]);
            float zz = sigf(a1[r] + gz + bz[r]);
            float nn = tanhf_(a2[r] + bni[r] + rr * (gn + bnh[r]));
            float h  = (1.0f - zz) * nn + zz * h2l[r];
            h2l[r] = h; hq[r] = f2bf(h);
          }
          st8c(h2b + ((k - 1) % 2) * kBH + bb * kH + u0 + q * 4, hq[0], hq[1], hq[2], hq[3]);
        }
      }
      gbar(slots, wg, (u32)(k + 1));
    }
  } else {
    // ---------------- output head ----------------
    const int g3 = wg - 128;
    const int bb = g3 * 16 + l15;
    const int mat = wid & 1, rt = wid >> 1;   // mat0: w_o1 branch + store; mat1: w_o2 branch
    const float* wo = mat ? wo2 : wo1;
    const float* bo = mat ? bo2 : bo1;
    const int row = rt * 16 + l15;            // output channel (rows >= 24 padded with 0)
    bf16x8 zf = {0,0,0,0,0,0,0,0};
    bf16x8 af[16];
#pragma unroll
    for (int c = 0; c < 16; ++c)
      af[c] = (row < kO) ? cvt8(wo + row * kH + c * 32 + q * 8) : zf;
    float bv[4];
#pragma unroll
    for (int r = 0; r < 4; ++r) {
      int o = rt * 16 + q * 4 + r;
      bv[r] = (o < kO) ? bo[o] : 0.0f;
    }
    for (int k = 0; k < kTicks; ++k) {
      if (k >= 2) {
        const int t = k - 2;  // out[t] = tanh(h1[t]@wo1^T+b) + tanh(h2[t]@wo2^T+b)
        const u16* hs = (mat == 0)
            ? h1b + (t % 3) * kBH + bb * kH
            : h2b + (t % 2) * kBH + bb * kH;
        f32x4 a0 = {0,0,0,0};
#pragma unroll
        for (int c = 0; c < 16; ++c)
          a0 = mfma(af[c], ld8c(hs + c * 32 + q * 8), a0);
        float v[4];
#pragma unroll
        for (int r = 0; r < 4; ++r) v[r] = tanhf_(a0[r] + bv[r]);
        if (mat == 1) {
#pragma unroll
          for (int r = 0; r < 4; ++r) xch[rt][0][lane][r] = v[r];
        }
        __syncthreads();
        if (mat == 0) {
          int o0 = rt * 16 + q * 4;
          if (o0 < kO) {
            float4 ov;
            ov.x = v[0] + xch[rt][0][lane][0];
            ov.y = v[1] + xch[rt][0][lane][1];
            ov.z = v[2] + xch[rt][0][lane][2];
            ov.w = v[3] + xch[rt][0][lane][3];
            *reinterpret_cast<float4*>(out + (bb * kT + t) * kO + o0) = ov;
          }
        }
      }
      gbar(slots, wg, (u32)(k + 1));
    }
  }
}

extern "C" void kernel_launch(void* const* d_in, const int* in_sizes, int n_in,
                              void* d_out, int out_size, void* d_ws, size_t ws_size,
                              hipStream_t stream) {
  (void)in_sizes; (void)n_in; (void)out_size; (void)ws_size; (void)kB;
  // zero h buffers + barrier slots (ws is poisoned 0xAA before every launch)
  hipMemsetAsync(d_ws, 0, kBarOff + 1024, stream);
  const float* x    = (const float*)d_in[0];
  const float* wih1 = (const float*)d_in[1];
  const float* whh1 = (const float*)d_in[2];
  const float* bih1 = (const float*)d_in[3];
  const float* bhh1 = (const float*)d_in[4];
  const float* wih2 = (const float*)d_in[5];
  const float* whh2 = (const float*)d_in[6];
  const float* bih2 = (const float*)d_in[7];
  const float* bhh2 = (const float*)d_in[8];
  const float* wo1  = (const float*)d_in[9];
  const float* bo1  = (const float*)d_in[10];
  const float* wo2  = (const float*)d_in[11];
  const float* bo2  = (const float*)d_in[12];
  float* out  = (float*)d_out;
  u16* hbuf   = (u16*)d_ws;
  u32* slots  = (u32*)((char*)d_ws + kBarOff);
  stackgru<<<dim3(kNWG), dim3(256), 0, stream>>>(
      x, wih1, whh1, bih1, bhh1, wih2, whh2, bih2, bhh2,
      wo1, bo1, wo2, bo2, out, hbuf, slots);
}

// Round 4
// 7128.139 us; speedup vs baseline: 1.7752x; 1.1191x over previous
//
#include <hip/hip_runtime.h>

typedef unsigned short u16;
typedef unsigned int u32;
typedef unsigned long long u64;
typedef __attribute__((ext_vector_type(8))) short bf16x8;   // 8 bf16 = 4 VGPRs (guide §3)
typedef __attribute__((ext_vector_type(4))) float f32x4;

namespace {
constexpr int kB = 64, kT = 1024, kI = 64, kH = 512, kO = 24;
constexpr int kBH = kB * kH;                 // 32768 elements per h buffer (bf16)
constexpr int kNWG = 132;                    // 64 L1 + 64 L2 + 4 OUT
// h1: 4 bufs (mod 4), h2: 2 bufs (mod 2)
constexpr unsigned kBarOff = 6u * (unsigned)kBH * 2u;  // 393216 bytes
}

__device__ __forceinline__ u16 f2bf(float f) {   // round-to-nearest-even
  union { float f; u32 u; } c; c.f = f;
  u32 u = c.u + 0x7FFFu + ((c.u >> 16) & 1u);
  return (u16)(u >> 16);
}
__device__ __forceinline__ float sigf(float x) { return 1.0f / (1.0f + __expf(-x)); }
__device__ __forceinline__ float tanhf_(float x) {
  float e = __expf(2.0f * x); return 1.0f - 2.0f / (e + 1.0f);  // safe at +-inf
}
// load 8 consecutive fp32, convert to a bf16x8 MFMA fragment (RNE)
__device__ __forceinline__ bf16x8 cvt8(const float* p) {
  const float4 f0 = *reinterpret_cast<const float4*>(p);
  const float4 f1 = *reinterpret_cast<const float4*>(p + 4);
  bf16x8 r;
  r[0] = (short)f2bf(f0.x); r[1] = (short)f2bf(f0.y);
  r[2] = (short)f2bf(f0.z); r[3] = (short)f2bf(f0.w);
  r[4] = (short)f2bf(f1.x); r[5] = (short)f2bf(f1.y);
  r[6] = (short)f2bf(f1.z); r[7] = (short)f2bf(f1.w);
  return r;
}
// coherent (cross-XCD) 16B load of 8 bf16 -> sc0 sc1, served at the coherent point
__device__ __forceinline__ bf16x8 ld8c(const u16* p) {
  union { bf16x8 v; u64 q[2]; } r;
  r.q[0] = __hip_atomic_load((const u64*)p,     __ATOMIC_RELAXED, __HIP_MEMORY_SCOPE_AGENT);
  r.q[1] = __hip_atomic_load((const u64*)p + 1, __ATOMIC_RELAXED, __HIP_MEMORY_SCOPE_AGENT);
  return r.v;
}
// coherent 8B store of 4 bf16 (write-through past L2 to the coherent point)
__device__ __forceinline__ void st8c(u16* p, u16 a, u16 b, u16 c, u16 d) {
  u64 v = (u64)a | ((u64)b << 16) | ((u64)c << 32) | ((u64)d << 48);
  __hip_atomic_store((u64*)p, v, __ATOMIC_RELAXED, __HIP_MEMORY_SCOPE_AGENT);
}
__device__ __forceinline__ f32x4 mfma(bf16x8 a, bf16x8 b, f32x4 c) {
  return __builtin_amdgcn_mfma_f32_16x16x32_bf16(a, b, c, 0, 0, 0);
}
__device__ __forceinline__ int ldslot(const int* s, int i) {
  return __hip_atomic_load(&s[i], __ATOMIC_RELAXED, __HIP_MEMORY_SCOPE_AGENT);
}

// Per-wave dependency polls. Counters are monotone; checking anti-deps early
// (top of tick) is conservative-safe. All deps fold into ONE lane-parallel
// load round trip per iteration; s_sleep backoff caps L3 poll traffic.
// (a) lanes 0..31 watch s[base+lane] >= thr
__device__ __forceinline__ void poll1(const int* s, int base, int thr) {
  const int lane = threadIdx.x & 63;
  int it = 0;
  for (;;) {
    int a = (lane < 32) ? ldslot(s, base + lane) : 0x7fffffff;
    if (__all(a >= thr)) break;
    if (++it > 2) __builtin_amdgcn_s_sleep(1);
  }
  __asm__ volatile("" ::: "memory");
}
// (b) lanes 0..31: s[baseA+lane]>=thrA ; lanes 0..n2-1 second load s[base2+lane]>=thr2
__device__ __forceinline__ void poll1b(const int* s, int baseA, int thrA,
                                       int base2, int n2, int thr2) {
  const int lane = threadIdx.x & 63;
  int it = 0;
  for (;;) {
    int a = (lane < 32) ? ldslot(s, baseA + lane) : 0x7fffffff;
    int b = (lane < n2) ? ldslot(s, base2 + lane) : 0x7fffffff;
    if (__all((a >= thrA) & (b >= thr2))) break;
    if (++it > 2) __builtin_amdgcn_s_sleep(1);
  }
  __asm__ volatile("" ::: "memory");
}
// (c) lanes 0..31: peers>=thrA ; lanes 32..63: s[baseB+lane-32]>=thrB ; + 2-slot set
__device__ __forceinline__ void poll2b(const int* s, int baseA, int thrA,
                                       int baseB, int thrB,
                                       int base2, int thr2) {
  const int lane = threadIdx.x & 63;
  const int idx = (lane < 32) ? (baseA + lane) : (baseB + lane - 32);
  const int thr = (lane < 32) ? thrA : thrB;
  int it = 0;
  for (;;) {
    int a = ldslot(s, idx);
    int b = (lane < 2) ? ldslot(s, base2 + lane) : 0x7fffffff;
    if (__all((a >= thr) & (b >= thr2))) break;
    if (++it > 2) __builtin_amdgcn_s_sleep(1);
  }
  __asm__ volatile("" ::: "memory");
}

// Roles (grid of 132 x 256 threads, free-running, counter-synchronized):
//   wg   0..63 : layer-1 GRU, 16 hidden units x 32 batch. own tick k -> h1[k]
//   wg  64..127: layer-2 GRU, 16 units x 32 batch.        own tick k -> h2[k]
//   wg 128..131: output head, 16 batch each.              own tick k -> out[k-1]
// slots[w] = last tick completed by WG w (h stores globally visible first).
// Dependencies per tick k:
//   L1: peers(b0) >= k-1 | anti: L2(b0) >= k-4, OUTpair >= k-4   (h1 mod 4)
//   L2: mat0 wave: L1(b0) >= k, anti OUTpair >= k-2 ; mat1 wave: peers >= k-1
//   OUT: mat0: L1(half) >= k ; mat1: L2(half) >= k
// MFMA 16x16x32 frag conventions (guide §3, m89/m118-verified):
//   A: m=lane&15, k=quad*8+j ; B: n=lane&15, k=quad*8+j ; C/D: col(n)=lane&15, row(m)=quad*4+reg
__global__ __launch_bounds__(256, 1) void stackgru(
    const float* __restrict__ x,
    const float* __restrict__ wih1, const float* __restrict__ whh1,
    const float* __restrict__ bih1, const float* __restrict__ bhh1,
    const float* __restrict__ wih2, const float* __restrict__ whh2,
    const float* __restrict__ bih2, const float* __restrict__ bhh2,
    const float* __restrict__ wo1, const float* __restrict__ bo1,
    const float* __restrict__ wo2, const float* __restrict__ bo2,
    float* __restrict__ out, u16* __restrict__ hbuf, int* __restrict__ slots)
{
  __shared__ float xch[2][2][3][64][4];   // [tick parity][ntl][gate][lane][reg]
  const int wg = blockIdx.x;
  const int tid = threadIdx.x;
  const int lane = tid & 63;
  const int wid = tid >> 6;
  const int l15 = lane & 15;
  const int q = lane >> 4;

  u16* h1b = hbuf;                     // 4 * kBH
  u16* h2b = hbuf + 4 * kBH;           // 2 * kBH

  if (wg < 64) {
    // ---------------- layer 1 ----------------
    const int u0 = (wg & 31) * 16, b0 = (wg >> 5) * 32;
    const int ntl = wid & 1, kh = wid >> 1;   // kh: K-half; ntl: batch 16-group
    const int bb = b0 + ntl * 16 + l15;       // batch row this lane produces
    const int pbase = (wg >> 5) * 32;         // L1 peers (same b0)
    const int l2base = 64 + (wg >> 5) * 32;   // L2 WGs same b0 (anti-dep)
    const int obase = 128 + (b0 >> 4);        // 2 OUT WGs covering b0..b0+32
    bf16x8 ahh[3][8];                          // w_hh1 A-frags resident in VGPRs
#pragma unroll
    for (int g = 0; g < 3; ++g)
#pragma unroll
      for (int c = 0; c < 8; ++c)
        ahh[g][c] = cvt8(whh1 + (g * kH + u0 + l15) * kH + (kh * 8 + c) * 32 + q * 8);
    bf16x8 aih[3][2];
    float br[4], bz[4], bni[4], bnh[4], h1l[4];
    if (kh == 0) {
#pragma unroll
      for (int g = 0; g < 3; ++g)
#pragma unroll
        for (int c = 0; c < 2; ++c)
          aih[g][c] = cvt8(wih1 + (g * kH + u0 + l15) * kI + c * 32 + q * 8);
#pragma unroll
      for (int r = 0; r < 4; ++r) {
        int u = u0 + q * 4 + r;
        br[r]  = bih1[u]          + bhh1[u];
        bz[r]  = bih1[kH + u]     + bhh1[kH + u];
        bni[r] = bih1[2 * kH + u];
        bnh[r] = bhh1[2 * kH + u];
        h1l[r] = 0.0f;                  // fp32 master copy of h1 stays in regs
      }
    }
    for (int k = 1; k <= kT; ++k) {
      const int par = k & 1;
      // prefetch x (no dependency) before the poll to hide its latency
      bf16x8 xf0, xf1;
      if (kh == 0) {
        const float* xs = x + (bb * kT + (k - 1)) * kI + q * 8;
        xf0 = cvt8(xs); xf1 = cvt8(xs + 32);
      }
      poll2b(slots, pbase, k - 1, l2base, k - 4, obase, k - 4);
      const u16* hs = h1b + ((k - 1) & 3) * kBH + bb * kH + kh * 256;  // h1[k-1]
      f32x4 a0 = {0,0,0,0}, a1 = {0,0,0,0}, a2 = {0,0,0,0};
#pragma unroll
      for (int c = 0; c < 8; ++c) {
        bf16x8 bf = ld8c(hs + c * 32 + q * 8);
        a0 = mfma(ahh[0][c], bf, a0);
        a1 = mfma(ahh[1][c], bf, a1);
        a2 = mfma(ahh[2][c], bf, a2);
      }
      f32x4 x0 = {0,0,0,0}, x1 = {0,0,0,0}, x2 = {0,0,0,0};
      if (kh == 1) {
#pragma unroll
        for (int r = 0; r < 4; ++r) {
          xch[par][ntl][0][lane][r] = a0[r];
          xch[par][ntl][1][lane][r] = a1[r];
          xch[par][ntl][2][lane][r] = a2[r];
        }
      } else {
        x0 = mfma(aih[0][0], xf0, x0); x0 = mfma(aih[0][1], xf1, x0);
        x1 = mfma(aih[1][0], xf0, x1); x1 = mfma(aih[1][1], xf1, x1);
        x2 = mfma(aih[2][0], xf0, x2); x2 = mfma(aih[2][1], xf1, x2);
      }
      __syncthreads();
      if (kh == 0) {
        u16 hq[4];
#pragma unroll
        for (int r = 0; r < 4; ++r) {
          float gr = a0[r] + xch[par][ntl][0][lane][r];
          float gz = a1[r] + xch[par][ntl][1][lane][r];
          float gn = a2[r] + xch[par][ntl][2][lane][r];
          float rr = sigf(x0[r] + gr + br[r]);
          float zz = sigf(x1[r] + gz + bz[r]);
          float nn = tanhf_(x2[r] + bni[r] + rr * (gn + bnh[r]));
          float h  = (1.0f - zz) * nn + zz * h1l[r];
          h1l[r] = h; hq[r] = f2bf(h);
        }
        st8c(h1b + (k & 3) * kBH + bb * kH + u0 + q * 4, hq[0], hq[1], hq[2], hq[3]);
      }
      __syncthreads();                       // all waves' h stores drained (vmcnt 0)
      if (tid == 0)
        __hip_atomic_store(&slots[wg], k, __ATOMIC_RELAXED, __HIP_MEMORY_SCOPE_AGENT);
    }
  } else if (wg < 128) {
    // ---------------- layer 2 ----------------
    const int g2 = wg - 64;
    const int u0 = (g2 & 31) * 16, b0 = (g2 >> 5) * 32;
    const int ntl = wid & 1, mat = wid >> 1;  // mat0: gi2 (w_ih2) + update; mat1: gh2 (w_hh2)
    const int bb = b0 + ntl * 16 + l15;
    const int l1base = (g2 >> 5) * 32;        // L1 same b0
    const int pbase = 64 + (g2 >> 5) * 32;    // L2 peers
    const int obase = 128 + (b0 >> 4);
    const float* wsrc = mat ? whh2 : wih2;
    bf16x8 af[3][16];                          // 192 VGPRs of resident weights
#pragma unroll
    for (int g = 0; g < 3; ++g)
#pragma unroll
      for (int c = 0; c < 16; ++c)
        af[g][c] = cvt8(wsrc + (g * kH + u0 + l15) * kH + c * 32 + q * 8);
    float br[4], bz[4], bni[4], bnh[4], h2l[4];
    if (mat == 0) {
#pragma unroll
      for (int r = 0; r < 4; ++r) {
        int u = u0 + q * 4 + r;
        br[r]  = bih2[u]          + bhh2[u];
        bz[r]  = bih2[kH + u]     + bhh2[kH + u];
        bni[r] = bih2[2 * kH + u];
        bnh[r] = bhh2[2 * kH + u];
        h2l[r] = 0.0f;
      }
    }
    for (int k = 1; k <= kT; ++k) {
      const int par = k & 1;
      if (mat == 0) poll1b(slots, l1base, k, obase, 2, k - 2);
      else          poll1(slots, pbase, k - 1);
      // mat0: gi2 from h1[k] (slot k%4); mat1: gh2 from h2[k-1] (slot (k-1)%2)
      const u16* hs = (mat == 0)
          ? h1b + (k & 3) * kBH + bb * kH
          : h2b + ((k - 1) & 1) * kBH + bb * kH;
      f32x4 a0 = {0,0,0,0}, a1 = {0,0,0,0}, a2 = {0,0,0,0};
#pragma unroll
      for (int c = 0; c < 16; ++c) {
        bf16x8 bf = ld8c(hs + c * 32 + q * 8);
        a0 = mfma(af[0][c], bf, a0);
        a1 = mfma(af[1][c], bf, a1);
        a2 = mfma(af[2][c], bf, a2);
      }
      if (mat == 1) {
#pragma unroll
        for (int r = 0; r < 4; ++r) {
          xch[par][ntl][0][lane][r] = a0[r];
          xch[par][ntl][1][lane][r] = a1[r];
          xch[par][ntl][2][lane][r] = a2[r];
        }
      }
      __syncthreads();
      if (mat == 0) {
        u16 hq[4];
#pragma unroll
        for (int r = 0; r < 4; ++r) {
          float gr = xch[par][ntl][0][lane][r];
          float gz = xch[par][ntl][1][lane][r];
          float gn = xch[par][ntl][2][lane][r];
          float rr = sigf(a0[r] + gr + br[r]);
          float zz = sigf(a1[r] + gz + bz[r]);
          float nn = tanhf_(a2[r] + bni[r] + rr * (gn + bnh[r]));
          float h  = (1.0f - zz) * nn + zz * h2l[r];
          h2l[r] = h; hq[r] = f2bf(h);
        }
        st8c(h2b + (k & 1) * kBH + bb * kH + u0 + q * 4, hq[0], hq[1], hq[2], hq[3]);
      }
      __syncthreads();
      if (tid == 0)
        __hip_atomic_store(&slots[wg], k, __ATOMIC_RELAXED, __HIP_MEMORY_SCOPE_AGENT);
    }
  } else {
    // ---------------- output head ----------------
    const int g3 = wg - 128;
    const int bb = g3 * 16 + l15;
    const int mat = wid & 1, rt = wid >> 1;   // mat0: w_o1 branch + store; mat1: w_o2 branch
    const int l1base = (g3 >> 1) * 32;
    const int l2base = 64 + (g3 >> 1) * 32;
    const float* wo = mat ? wo2 : wo1;
    const float* bo = mat ? bo2 : bo1;
    const int row = rt * 16 + l15;            // output channel (rows >= 24 padded 0)
    bf16x8 zf = {0,0,0,0,0,0,0,0};
    bf16x8 af[16];
#pragma unroll
    for (int c = 0; c < 16; ++c)
      af[c] = (row < kO) ? cvt8(wo + row * kH + c * 32 + q * 8) : zf;
    float bv[4];
#pragma unroll
    for (int r = 0; r < 4; ++r) {
      int o = rt * 16 + q * 4 + r;
      bv[r] = (o < kO) ? bo[o] : 0.0f;
    }
    for (int k = 1; k <= kT; ++k) {
      const int par = k & 1;
      if (mat == 0) poll1(slots, l1base, k);
      else          poll1(slots, l2base, k);
      const int t = k - 1;  // out[t] = tanh(h1[k]@wo1^T+b) + tanh(h2[k]@wo2^T+b)
      const u16* hs = (mat == 0)
          ? h1b + (k & 3) * kBH + bb * kH
          : h2b + (k & 1) * kBH + bb * kH;
      f32x4 a0 = {0,0,0,0};
#pragma unroll
      for (int c = 0; c < 16; ++c)
        a0 = mfma(af[c], ld8c(hs + c * 32 + q * 8), a0);
      float v[4];
#pragma unroll
      for (int r = 0; r < 4; ++r) v[r] = tanhf_(a0[r] + bv[r]);
      if (mat == 1) {
#pragma unroll
        for (int r = 0; r < 4; ++r) xch[par][rt][0][lane][r] = v[r];
      }
      __syncthreads();
      if (mat == 0) {
        int o0 = rt * 16 + q * 4;
        if (o0 < kO) {
          float4 ov;
          ov.x = v[0] + xch[par][rt][0][lane][0];
          ov.y = v[1] + xch[par][rt][0][lane][1];
          ov.z = v[2] + xch[par][rt][0][lane][2];
          ov.w = v[3] + xch[par][rt][0][lane][3];
          *reinterpret_cast<float4*>(out + (bb * kT + t) * kO + o0) = ov;
        }
      }
      __syncthreads();
      if (tid == 0)
        __hip_atomic_store(&slots[wg], k, __ATOMIC_RELAXED, __HIP_MEMORY_SCOPE_AGENT);
    }
  }
}

extern "C" void kernel_launch(void* const* d_in, const int* in_sizes, int n_in,
                              void* d_out, int out_size, void* d_ws, size_t ws_size,
                              hipStream_t stream) {
  (void)in_sizes; (void)n_in; (void)out_size; (void)ws_size; (void)kB; (void)kNWG;
  // zero h buffers + progress slots (ws is poisoned 0xAA before every launch)
  hipMemsetAsync(d_ws, 0, kBarOff + 1024, stream);
  const float* x    = (const float*)d_in[0];
  const float* wih1 = (const float*)d_in[1];
  const float* whh1 = (const float*)d_in[2];
  const float* bih1 = (const float*)d_in[3];
  const float* bhh1 = (const float*)d_in[4];
  const float* wih2 = (const float*)d_in[5];
  const float* whh2 = (const float*)d_in[6];
  const float* bih2 = (const float*)d_in[7];
  const float* bhh2 = (const float*)d_in[8];
  const float* wo1  = (const float*)d_in[9];
  const float* bo1  = (const float*)d_in[10];
  const float* wo2  = (const float*)d_in[11];
  const float* bo2  = (const float*)d_in[12];
  float* out  = (float*)d_out;
  u16* hbuf   = (u16*)d_ws;
  int* slots  = (int*)((char*)d_ws + kBarOff);
  stackgru<<<dim3(kNWG), dim3(256), 0, stream>>>(
      x, wih1, whh1, bih1, bhh1, wih2, whh2, bih2, bhh2,
      wo1, bo1, wo2, bo2, out, hbuf, slots);
}

// Round 5
// 6206.829 us; speedup vs baseline: 2.0387x; 1.1484x over previous
//
#include <hip/hip_runtime.h>

typedef unsigned short u16;
typedef unsigned int u32;
typedef unsigned long long u64;
typedef __attribute__((ext_vector_type(8))) short bf16x8;   // 8 bf16 = 4 VGPRs
typedef __attribute__((ext_vector_type(4))) float f32x4;

namespace {
constexpr int kT = 1024, kI = 64, kH = 512, kO = 24;
constexpr int kB = 64;
constexpr int kBH = kB * kH;                  // 32768 elems per h buffer (bf16)
constexpr int kNWG = 132;                     // 64 L1 + 64 L2 + 4 OUT
constexpr unsigned kBarOff = 6u * (unsigned)kBH * 2u;  // 3 h1 bufs + 3 h2 bufs = 393216 B
}

__device__ __forceinline__ u16 f2bf(float f) {   // round-to-nearest-even
  union { float f; u32 u; } c; c.f = f;
  u32 u = c.u + 0x7FFFu + ((c.u >> 16) & 1u);
  return (u16)(u >> 16);
}
__device__ __forceinline__ float sigf(float x) { return 1.0f / (1.0f + __expf(-x)); }
__device__ __forceinline__ float tanhf_(float x) {
  float e = __expf(2.0f * x); return 1.0f - 2.0f / (e + 1.0f);  // safe at +-inf
}
__device__ __forceinline__ bf16x8 cvt8(const float* p) {  // fp32x8 -> bf16x8 (RNE)
  const float4 f0 = *reinterpret_cast<const float4*>(p);
  const float4 f1 = *reinterpret_cast<const float4*>(p + 4);
  bf16x8 r;
  r[0] = (short)f2bf(f0.x); r[1] = (short)f2bf(f0.y);
  r[2] = (short)f2bf(f0.z); r[3] = (short)f2bf(f0.w);
  r[4] = (short)f2bf(f1.x); r[5] = (short)f2bf(f1.y);
  r[6] = (short)f2bf(f1.z); r[7] = (short)f2bf(f1.w);
  return r;
}
// coherent (cross-XCD) 16B load: two relaxed agent-scope u64 loads (sc0 sc1)
__device__ __forceinline__ bf16x8 ld8c(const u16* p) {
  union { bf16x8 v; u64 q[2]; } r;
  r.q[0] = __hip_atomic_load((const u64*)p,     __ATOMIC_RELAXED, __HIP_MEMORY_SCOPE_AGENT);
  r.q[1] = __hip_atomic_load((const u64*)p + 1, __ATOMIC_RELAXED, __HIP_MEMORY_SCOPE_AGENT);
  return r.v;
}
__device__ __forceinline__ f32x4 mfma(bf16x8 a, bf16x8 b, f32x4 c) {
  return __builtin_amdgcn_mfma_f32_16x16x32_bf16(a, b, c, 0, 0, 0);
}
__device__ __forceinline__ int ldslot(const int* s, int i) {
  return __hip_atomic_load(&s[i], __ATOMIC_RELAXED, __HIP_MEMORY_SCOPE_AGENT);
}
// tick tag (k mod 4) embedded in LSBs of bf16 elems 0,1 of each 8B granule
__device__ __forceinline__ u32 tagpat(int k) {
  return ((u32)k & 1u) | ((((u32)k >> 1) & 1u) << 16);
}
// tagged h store: 4 bf16 with 2 LSB tag bits, one atomic 8B store (all-or-nothing)
__device__ __forceinline__ void st_h(u16* p, const float* h, int k) {
  u16 a = (u16)((f2bf(h[0]) & ~1u) | ((u32)k & 1u));
  u16 b = (u16)((f2bf(h[1]) & ~1u) | (((u32)k >> 1) & 1u));
  u16 c = f2bf(h[2]); u16 d = f2bf(h[3]);
  u64 v = (u64)a | ((u64)b << 16) | ((u64)c << 32) | ((u64)d << 48);
  __hip_atomic_store((u64*)p, v, __ATOMIC_RELAXED, __HIP_MEMORY_SCOPE_AGENT);
}
// poll N 16B chunks until every 8B granule carries tag `pat`; on exit `ch` holds
// the verified data (poll == load; all N chunks in flight per round)
template<int N>
__device__ __forceinline__ void pollN(const u16* p, u32 pat, bf16x8* ch) {
  for (;;) {
    bool ok = true;
#pragma unroll
    for (int c = 0; c < N; ++c) ch[c] = ld8c(p + c * 32);
#pragma unroll
    for (int c = 0; c < N; ++c) {
      union { bf16x8 v; u32 u[4]; } t; t.v = ch[c];
      ok = ok && ((t.u[0] & 0x10001u) == pat) && ((t.u[2] & 0x10001u) == pat);
    }
    if (__all(ok)) break;
  }
  __asm__ volatile("" ::: "memory");
}
// amortized producer throttle: ensure watched consumer slots >= k-3 before
// overwriting the (k-3) buffer; opportunistically caches headroom
__device__ __forceinline__ void throttle(const int* slots, int baseA, int nA,
                                         int baseB, int nB, int k, int& bound) {
  if (bound >= k - 3) return;
  const int lane = threadIdx.x & 63;
  int idx = -1;
  if (lane < nA) idx = baseA + lane;
  else if (lane < nA + nB) idx = baseB + (lane - nA);
  for (;;) {
    int v = (idx >= 0) ? ldslot(slots, idx) : 0x7fffffff;
    if (__all(v >= k - 3)) { bound = __all(v >= k) ? k : (k - 3); break; }
    __builtin_amdgcn_s_sleep(2);
  }
}

// Roles (132 WGs x 512 threads, free-running, tag-synchronized dataflow):
//   wg   0..63 : layer-1 GRU, 16 units x 32 batch; waves = ntl(2) x kh(4 K-quarters)
//   wg  64..127: layer-2 GRU, 16 units x 32 batch; waves = ntl(2) x mat(2) x kh(2)
//   wg 128..131: output head, 16 batch; waves = mat(2) x kh(2) x rt(2 M-tiles)
// h1,h2: 3 bufs each (k mod 3), tags k mod 4 -> overwrite-safe to distance 12.
// MFMA 16x16x32 frags: A m=l15,k=q*8+j ; B n=l15,k=q*8+j ; C/D col=l15,row=q*4+r
__global__ __launch_bounds__(512, 1) void stackgru(
    const float* __restrict__ x,
    const float* __restrict__ wih1, const float* __restrict__ whh1,
    const float* __restrict__ bih1, const float* __restrict__ bhh1,
    const float* __restrict__ wih2, const float* __restrict__ whh2,
    const float* __restrict__ bih2, const float* __restrict__ bhh2,
    const float* __restrict__ wo1, const float* __restrict__ bo1,
    const float* __restrict__ wo2, const float* __restrict__ bo2,
    float* __restrict__ out, u16* __restrict__ hbuf, int* __restrict__ slots)
{
  __shared__ float red[2][3][3][64][4];   // [ntl|rt][srcWave][gate][lane][r] 36 KB
  const int wg = blockIdx.x;
  const int tid = threadIdx.x;
  const int lane = tid & 63;
  const int w = tid >> 6;
  const int l15 = lane & 15;
  const int q = lane >> 4;

  u16* h1b = hbuf;                     // 3 * kBH
  u16* h2b = hbuf + 3 * kBH;           // 3 * kBH

  if (wg < 64) {
    // ---------------- layer 1 ----------------
    const int u0 = (wg & 31) * 16, g = wg >> 5, b0 = g * 32;
    const int ntl = w & 1, kh = w >> 1;        // kh = K-quarter (0..3)
    const int bb = b0 + ntl * 16 + l15;
    bf16x8 ahh[3][4];                           // w_hh1 frags: 48 VGPRs
#pragma unroll
    for (int gg = 0; gg < 3; ++gg)
#pragma unroll
      for (int c = 0; c < 4; ++c)
        ahh[gg][c] = cvt8(whh1 + (gg * kH + u0 + l15) * kH + (kh * 4 + c) * 32 + q * 8);
    bf16x8 aih[3][2];
    float br[4], bz[4], bni[4], bnh[4], h1l[4];
    int bound = 0;
    if (kh == 0) {
#pragma unroll
      for (int gg = 0; gg < 3; ++gg)
#pragma unroll
        for (int c = 0; c < 2; ++c)
          aih[gg][c] = cvt8(wih1 + (gg * kH + u0 + l15) * kI + c * 32 + q * 8);
#pragma unroll
      for (int r = 0; r < 4; ++r) {
        int u = u0 + q * 4 + r;
        br[r]  = bih1[u]          + bhh1[u];
        bz[r]  = bih1[kH + u]     + bhh1[kH + u];
        bni[r] = bih1[2 * kH + u];
        bnh[r] = bhh1[2 * kH + u];
        h1l[r] = 0.0f;                  // fp32 master copy of h1 stays in regs
      }
    }
    for (int k = 1; k <= kT; ++k) {
      bf16x8 xf0, xf1;
      if (kh == 0) {                    // x prefetch (plain cached loads)
        const float* xs = x + (bb * kT + (k - 1)) * kI + q * 8;
        xf0 = cvt8(xs); xf1 = cvt8(xs + 32);
      }
      bf16x8 ch[4];
      pollN<4>(h1b + ((k - 1) % 3) * kBH + bb * kH + kh * 128 + q * 8,
               tagpat(k - 1), ch);      // h1[k-1], this wave's K-quarter
      f32x4 a0 = {0,0,0,0}, a1 = {0,0,0,0}, a2 = {0,0,0,0};
#pragma unroll
      for (int c = 0; c < 4; ++c) {
        a0 = mfma(ahh[0][c], ch[c], a0);
        a1 = mfma(ahh[1][c], ch[c], a1);
        a2 = mfma(ahh[2][c], ch[c], a2);
      }
      f32x4 x0 = {0,0,0,0}, x1 = {0,0,0,0}, x2 = {0,0,0,0};
      if (kh != 0) {
#pragma unroll
        for (int r = 0; r < 4; ++r) {
          red[ntl][kh - 1][0][lane][r] = a0[r];
          red[ntl][kh - 1][1][lane][r] = a1[r];
          red[ntl][kh - 1][2][lane][r] = a2[r];
        }
      } else {
        x0 = mfma(aih[0][0], xf0, x0); x0 = mfma(aih[0][1], xf1, x0);
        x1 = mfma(aih[1][0], xf0, x1); x1 = mfma(aih[1][1], xf1, x1);
        x2 = mfma(aih[2][0], xf0, x2); x2 = mfma(aih[2][1], xf1, x2);
        throttle(slots, 64 + g * 32, 32, 128 + g * 2, 2, k, bound);  // h1 anti-dep
      }
      __syncthreads();
      if (kh == 0) {
        float hnew[4];
#pragma unroll
        for (int r = 0; r < 4; ++r) {
          float gh0 = a0[r] + red[ntl][0][0][lane][r] + red[ntl][1][0][lane][r] + red[ntl][2][0][lane][r];
          float gh1 = a1[r] + red[ntl][0][1][lane][r] + red[ntl][1][1][lane][r] + red[ntl][2][1][lane][r];
          float gh2 = a2[r] + red[ntl][0][2][lane][r] + red[ntl][1][2][lane][r] + red[ntl][2][2][lane][r];
          float rr = sigf(x0[r] + gh0 + br[r]);
          float zz = sigf(x1[r] + gh1 + bz[r]);
          float nn = tanhf_(x2[r] + bni[r] + rr * (gh2 + bnh[r]));
          float h  = (1.0f - zz) * nn + zz * h1l[r];
          h1l[r] = h; hnew[r] = h;
        }
        st_h(h1b + (k % 3) * kBH + bb * kH + u0 + q * 4, hnew, k);
      }
      __syncthreads();                  // protect LDS partials for next tick
    }
  } else if (wg < 128) {
    // ---------------- layer 2 ----------------
    const int g2 = wg - 64;
    const int u0 = (g2 & 31) * 16, g = g2 >> 5, b0 = g * 32;
    const int ntl = w & 1, mat = (w >> 1) & 1, kh = w >> 2;  // kh = K-half
    const int bb = b0 + ntl * 16 + l15;
    const float* wsrc = mat ? whh2 : wih2;
    bf16x8 af[3][8];                            // 96 VGPRs of resident weights
#pragma unroll
    for (int gg = 0; gg < 3; ++gg)
#pragma unroll
      for (int c = 0; c < 8; ++c)
        af[gg][c] = cvt8(wsrc + (gg * kH + u0 + l15) * kH + (kh * 8 + c) * 32 + q * 8);
    const bool upd = (mat == 0 && kh == 0);
    float br[4], bz[4], bni[4], bnh[4], h2l[4];
    int bound = 0;
    if (upd) {
#pragma unroll
      for (int r = 0; r < 4; ++r) {
        int u = u0 + q * 4 + r;
        br[r]  = bih2[u]          + bhh2[u];
        bz[r]  = bih2[kH + u]     + bhh2[kH + u];
        bni[r] = bih2[2 * kH + u];
        bnh[r] = bhh2[2 * kH + u];
        h2l[r] = 0.0f;
      }
    }
    for (int k = 1; k <= kT; ++k) {
      const u16* hs = (mat == 0)
          ? h1b + (k % 3) * kBH + bb * kH + kh * 256 + q * 8        // h1[k]
          : h2b + ((k - 1) % 3) * kBH + bb * kH + kh * 256 + q * 8; // h2[k-1]
      bf16x8 ch[8];
      pollN<8>(hs, tagpat(mat == 0 ? k : k - 1), ch);
      f32x4 a0 = {0,0,0,0}, a1 = {0,0,0,0}, a2 = {0,0,0,0};
#pragma unroll
      for (int c = 0; c < 8; ++c) {
        a0 = mfma(af[0][c], ch[c], a0);
        a1 = mfma(af[1][c], ch[c], a1);
        a2 = mfma(af[2][c], ch[c], a2);
      }
      if (!upd) {
        const int s = mat * 2 + kh - 1;   // (0,1)->0 (1,0)->1 (1,1)->2
#pragma unroll
        for (int r = 0; r < 4; ++r) {
          red[ntl][s][0][lane][r] = a0[r];
          red[ntl][s][1][lane][r] = a1[r];
          red[ntl][s][2][lane][r] = a2[r];
        }
      } else {
        throttle(slots, 128 + g * 2, 2, 0, 0, k, bound);   // h2 anti-dep (OUT)
      }
      __syncthreads();
      if (upd) {
        float hnew[4];
#pragma unroll
        for (int r = 0; r < 4; ++r) {
          float gi0 = a0[r] + red[ntl][0][0][lane][r];
          float gi1 = a1[r] + red[ntl][0][1][lane][r];
          float gi2 = a2[r] + red[ntl][0][2][lane][r];
          float gh0 = red[ntl][1][0][lane][r] + red[ntl][2][0][lane][r];
          float gh1 = red[ntl][1][1][lane][r] + red[ntl][2][1][lane][r];
          float gh2 = red[ntl][1][2][lane][r] + red[ntl][2][2][lane][r];
          float rr = sigf(gi0 + gh0 + br[r]);
          float zz = sigf(gi1 + gh1 + bz[r]);
          float nn = tanhf_(gi2 + bni[r] + rr * (gh2 + bnh[r]));
          float h  = (1.0f - zz) * nn + zz * h2l[r];
          h2l[r] = h; hnew[r] = h;
        }
        st_h(h2b + (k % 3) * kBH + bb * kH + u0 + q * 4, hnew, k);
      }
      if (tid == 0)                      // reads of h1[k]/h2[k-1] done (post-barrier)
        __hip_atomic_store(&slots[wg], k, __ATOMIC_RELAXED, __HIP_MEMORY_SCOPE_AGENT);
      __syncthreads();
    }
  } else {
    // ---------------- output head ----------------
    const int g3 = wg - 128;
    const int bb = g3 * 16 + l15;
    const int mat = w & 1, kh = (w >> 1) & 1, rt = w >> 2;
    const float* wsel = mat ? wo2 : wo1;
    const int row = rt * 16 + l15;
    bf16x8 zf = {0,0,0,0,0,0,0,0};
    bf16x8 af[8];
#pragma unroll
    for (int c = 0; c < 8; ++c)
      af[c] = (row < kO) ? cvt8(wsel + row * kH + (kh * 8 + c) * 32 + q * 8) : zf;
    const bool fin = (mat == 0 && kh == 0);
    float bv1[4], bv2[4];
    if (fin) {
#pragma unroll
      for (int r = 0; r < 4; ++r) {
        int o = rt * 16 + q * 4 + r;
        bv1[r] = (o < kO) ? bo1[o] : 0.0f;
        bv2[r] = (o < kO) ? bo2[o] : 0.0f;
      }
    }
    for (int k = 1; k <= kT; ++k) {
      const u16* hs = (mat == 0)
          ? h1b + (k % 3) * kBH + bb * kH + kh * 256 + q * 8
          : h2b + (k % 3) * kBH + bb * kH + kh * 256 + q * 8;
      bf16x8 ch[8];
      pollN<8>(hs, tagpat(k), ch);
      f32x4 a0 = {0,0,0,0};
#pragma unroll
      for (int c = 0; c < 8; ++c) a0 = mfma(af[c], ch[c], a0);
      if (!fin) {
        const int s = mat * 2 + kh - 1;
#pragma unroll
        for (int r = 0; r < 4; ++r) red[rt][s][0][lane][r] = a0[r];
      }
      __syncthreads();
      if (fin) {
        int o0 = rt * 16 + q * 4;
        if (o0 < kO) {
          float4 ov;
          float v0 = tanhf_(a0[0] + red[rt][0][0][lane][0] + bv1[0]) +
                     tanhf_(red[rt][1][0][lane][0] + red[rt][2][0][lane][0] + bv2[0]);
          float v1 = tanhf_(a0[1] + red[rt][0][0][lane][1] + bv1[1]) +
                     tanhf_(red[rt][1][0][lane][1] + red[rt][2][0][lane][1] + bv2[1]);
          float v2 = tanhf_(a0[2] + red[rt][0][0][lane][2] + bv1[2]) +
                     tanhf_(red[rt][1][0][lane][2] + red[rt][2][0][lane][2] + bv2[2]);
          float v3 = tanhf_(a0[3] + red[rt][0][0][lane][3] + bv1[3]) +
                     tanhf_(red[rt][1][0][lane][3] + red[rt][2][0][lane][3] + bv2[3]);
          ov.x = v0; ov.y = v1; ov.z = v2; ov.w = v3;
          *reinterpret_cast<float4*>(out + (bb * kT + (k - 1)) * kO + o0) = ov;
        }
      }
      if (tid == 0)
        __hip_atomic_store(&slots[wg], k, __ATOMIC_RELAXED, __HIP_MEMORY_SCOPE_AGENT);
      __syncthreads();
    }
  }
}

extern "C" void kernel_launch(void* const* d_in, const int* in_sizes, int n_in,
                              void* d_out, int out_size, void* d_ws, size_t ws_size,
                              hipStream_t stream) {
  (void)in_sizes; (void)n_in; (void)out_size; (void)ws_size;
  // zero h buffers (tag 0 == tick 0) + watermark slots
  hipMemsetAsync(d_ws, 0, kBarOff + 1024, stream);
  const float* x    = (const float*)d_in[0];
  const float* wih1 = (const float*)d_in[1];
  const float* whh1 = (const float*)d_in[2];
  const float* bih1 = (const float*)d_in[3];
  const float* bhh1 = (const float*)d_in[4];
  const float* wih2 = (const float*)d_in[5];
  const float* whh2 = (const float*)d_in[6];
  const float* bih2 = (const float*)d_in[7];
  const float* bhh2 = (const float*)d_in[8];
  const float* wo1  = (const float*)d_in[9];
  const float* bo1  = (const float*)d_in[10];
  const float* wo2  = (const float*)d_in[11];
  const float* bo2  = (const float*)d_in[12];
  float* out  = (float*)d_out;
  u16* hbuf   = (u16*)d_ws;
  int* slots  = (int*)((char*)d_ws + kBarOff);
  stackgru<<<dim3(kNWG), dim3(512), 0, stream>>>(
      x, wih1, whh1, bih1, bhh1, wih2, whh2, bih2, bhh2,
      wo1, bo1, wo2, bo2, out, hbuf, slots);
}